// Round 2
// baseline (59574.158 us; speedup 1.0000x reference)
//
#include <hip/hip_runtime.h>
#include <hip/hip_bf16.h>

#define DEVI __device__ __forceinline__

DEVI float sigm(float x){ return 1.f/(1.f+expf(-x)); }

// ---------------- transpose: out[b][c][r] = in[b][r][c] ----------------
__global__ void k_transpose(const float* __restrict__ in, float* __restrict__ out, int R, int C){
  int b = blockIdx.y;
  long n = (long)R*C;
  long i = (long)blockIdx.x*256 + threadIdx.x;
  if (i < n){
    int r = (int)(i / C), c = (int)(i % C);
    out[(long)b*n + (long)c*R + r] = in[(long)b*n + i];
  }
}

// ---------------- embedding gathers (D=200) ----------------
__global__ void k_gather(const float* __restrict__ emb, const int* __restrict__ tok, float* __restrict__ out){
  int row = blockIdx.x; int c = threadIdx.x;
  if (c < 200) out[(long)row*200 + c] = emb[(long)tok[row]*200 + c];
}
// out[(b,t)] = emb[ tok[ sel[b]*50 + t ] ]
__global__ void k_gather_sel(const float* __restrict__ emb, const int* __restrict__ tok, const int* __restrict__ sel, float* __restrict__ out){
  int t = blockIdx.x, b = blockIdx.y; int c = threadIdx.x;
  if (c < 200){
    int tk = tok[(long)sel[b]*50 + t];
    out[((long)b*50 + t)*200 + c] = emb[(long)tk*200 + c];
  }
}

// ---------------- fp32 GEMM: C = A(M,K) @ W(N,K)^T + bias, z-batched ----------------
__global__ __launch_bounds__(256) void k_gemm_nt(
    const float* __restrict__ A, const float* __restrict__ W,
    const float* __restrict__ bias, float* __restrict__ C,
    int M, int N, int K, long sA, long sW, long sC, long sBias)
{
  int bz = blockIdx.z;
  A += (long)bz*sA; W += (long)bz*sW; C += (long)bz*sC;
  if (bias) bias += (long)bz*sBias;
  int n0 = blockIdx.x*64, m0 = blockIdx.y*64;
  __shared__ float As[16][68];
  __shared__ float Ws[16][68];
  int tid = threadIdx.x;
  int tx = tid & 15, ty = tid >> 4;
  float acc[4][4] = {};
  int lr = tid >> 2;
  int lc0 = (tid & 3) << 2;
  for (int k0 = 0; k0 < K; k0 += 16){
    #pragma unroll
    for (int i=0;i<4;i++){
      int k = k0 + lc0 + i;
      int m = m0 + lr;
      As[lc0+i][lr] = (m < M && k < K) ? A[(long)m*K + k] : 0.f;
      int n = n0 + lr;
      Ws[lc0+i][lr] = (n < N && k < K) ? W[(long)n*K + k] : 0.f;
    }
    __syncthreads();
    #pragma unroll
    for (int kk=0;kk<16;kk++){
      float a0[4], w0[4];
      #pragma unroll
      for (int i=0;i<4;i++) a0[i] = As[kk][(ty<<2)+i];
      #pragma unroll
      for (int j=0;j<4;j++) w0[j] = Ws[kk][(tx<<2)+j];
      #pragma unroll
      for (int i=0;i<4;i++)
        #pragma unroll
        for (int j=0;j<4;j++)
          acc[i][j] += a0[i]*w0[j];
    }
    __syncthreads();
  }
  #pragma unroll
  for (int i=0;i<4;i++){
    int m = m0 + (ty<<2) + i;
    if (m >= M) continue;
    #pragma unroll
    for (int j=0;j<4;j++){
      int n = n0 + (tx<<2) + j;
      if (n < N) C[(long)m*N + n] = acc[i][j] + (bias ? bias[n] : 0.f);
    }
  }
}

// ---------------- small GRU (h=150, 3h=450), 1 wg per (item,dir) ----------------
// xs: [dir][item][T][450]; Wt: [dir][150][450] (Wt[k][j]=Whh[j][k]); bhh [dir][450]
__global__ __launch_bounds__(512) void k_gru_small(
    const float* __restrict__ xs, long xsDir,
    const float* __restrict__ Wt, const float* __restrict__ bhh,
    float* __restrict__ y, int yld,
    float* __restrict__ meanOut, int meanld,
    int T)
{
  int item = blockIdx.x, dir = blockIdx.y;
  const float* xsd = xs + (long)dir*xsDir + (long)item*T*450;
  const float* Wtd = Wt + (long)dir*150*450;
  int tid = threadIdx.x;
  float bh = (tid < 450) ? bhh[(long)dir*450 + tid] : 0.f;
  __shared__ float hs[152];
  __shared__ float gs[456];
  if (tid < 150) hs[tid] = 0.f;
  float hsum = 0.f;
  __syncthreads();
  for (int t=0;t<T;t++){
    int tt = dir ? (T-1-t) : t;
    if (tid < 450){
      float g = bh;
      const float* wp = Wtd + tid;
      for (int k=0;k<150;k++) g += hs[k] * wp[(long)k*450];
      gs[tid] = g;
    }
    __syncthreads();
    if (tid < 150){
      const float* xr = xsd + (long)tt*450;
      float r = sigm(xr[tid]     + gs[tid]);
      float z = sigm(xr[150+tid] + gs[150+tid]);
      float nn = tanhf(xr[300+tid] + r*gs[300+tid]);
      float h = (1.f-z)*nn + z*hs[tid];
      hs[tid] = h;
      hsum += h;
      if (y) y[((long)item*T + tt)*yld + dir*150 + tid] = h;
    }
    __syncthreads();
  }
  if (meanOut && tid < 150)
    meanOut[(long)item*meanld + dir*150 + tid] = hsum / (float)T;
}

// ---------------- big GRU, one launch per timestep ----------------
// grid (h/10, 4, 2), block 256. GB=8 batch items per wg, HC=10 h-cols per wg.
__global__ __launch_bounds__(256) void k_gru_bigstep(
    const float* __restrict__ xs, long xsDir,
    const float* __restrict__ Wt, const float* __restrict__ bhh,
    const float* __restrict__ hprev, float* __restrict__ hnext,
    float* __restrict__ ysum, int ysld,
    int t, int T, int h)
{
  const int HC=10, GB=8, B=32;
  int dir = blockIdx.z;
  int c0 = blockIdx.x*HC;
  int b0 = blockIdx.y*GB;
  int h3 = 3*h;
  const float* xsd = xs + (long)dir*xsDir;
  const float* Wtd = Wt + (long)dir*h*h3;
  const float* bhd = bhh + (long)dir*h3;
  const float* hp  = hprev + (long)dir*B*h;
  float* hn = hnext + (long)dir*B*h;
  int tt = dir ? (T-1-t) : t;
  __shared__ float hsl[8*600];
  __shared__ float gl[240];
  int tid = threadIdx.x;
  for (int i=tid; i<GB*h; i+=256)
    hsl[i] = hp[(long)(b0 + i/h)*h + (i%h)];
  __syncthreads();
  if (tid < 3*GB*HC){
    int i = tid % HC;
    int bb = (tid / HC) % GB;
    int g = tid / (HC*GB);
    int gcol = g*h + c0 + i;
    float acc = bhd[gcol];
    const float* hr = &hsl[bb*h];
    const float* wp = Wtd + gcol;
    for (int k=0;k<h;k++) acc += hr[k] * wp[(long)k*h3];
    gl[tid] = acc;
  }
  __syncthreads();
  if (tid < GB*HC){
    int i = tid % HC; int bb = tid / HC;
    int c = c0 + i; int b = b0 + bb;
    const float* xr = xsd + ((long)b*T + tt)*h3;
    float r = sigm(xr[c]     + gl[(0*GB+bb)*HC + i]);
    float z = sigm(xr[h+c]   + gl[(1*GB+bb)*HC + i]);
    float nn = tanhf(xr[2*h+c] + r*gl[(2*GB+bb)*HC + i]);
    float hv = hsl[bb*h + c];
    float hne = (1.f-z)*nn + z*hv;
    hn[(long)b*h + c] = hne;
    ysum[(long)b*ysld + dir*h + c] += hne;
  }
}

// ---------------- graph decomposition layer (D=300, K=8) ----------------
__global__ __launch_bounds__(256) void k_graphdecomp(
   const float* __restrict__ labIn, float* __restrict__ labOut,
   const int* __restrict__ nb, const int* __restrict__ nbm, int N)
{
  int n = blockIdx.x; if (n >= N) return;
  int tid = threadIdx.x;
  __shared__ float ln[300];
  __shared__ float red[12];
  for (int d=tid; d<300; d+=256) ln[d] = labIn[(long)n*300+d];
  float deg = 0.f;
  for (int k=0;k<8;k++) deg += (float)nbm[n*8+k];
  float invdeg = 1.f / fmaxf(deg, 1.f);
  float acc0 = 0.f, acc1 = 0.f;
  __syncthreads();
  for (int k=0;k<8;k++){
    int j = nb[n*8+k];
    float mk = (float)nbm[n*8+k];
    const float* lj = labIn + (long)j*300;
    float p1=0.f, p2=0.f;
    for (int d=tid; d<300; d+=256){ float v = lj[d]; p1 += ln[d]*v; p2 += v*v; }
    for (int o=32;o>0;o>>=1){ p1 += __shfl_down(p1,o); p2 += __shfl_down(p2,o); }
    __syncthreads();
    int w = tid>>6, lane = tid&63;
    if (lane==0){ red[w]=p1; red[4+w]=p2; }
    __syncthreads();
    float x1 = red[0]+red[1]+red[2]+red[3];
    float x2 = red[4]+red[5]+red[6]+red[7];
    float coef = (x1 / (x2 + 1e-10f)) * mk * invdeg;
    acc0 += coef * lj[tid];
    if (tid + 256 < 300) acc1 += coef * lj[tid+256];
    __syncthreads();
  }
  bool pos = deg > 0.f;
  labOut[(long)n*300 + tid]                       = pos ? (ln[tid]     - acc0) : ln[tid];
  if (tid+256 < 300) labOut[(long)n*300 + tid+256] = pos ? (ln[tid+256] - acc1) : ln[tid+256];
}

// ---------------- copy ----------------
__global__ void k_copy(const float* __restrict__ src, float* __restrict__ dst, long n){
  long i = (long)blockIdx.x*256+threadIdx.x; if (i<n) dst[i]=src[i];
}

// ---------------- code_wise reductions ----------------
// S: (16384,444). slices {new_charge,ori_a,new_article,ori_b}
__global__ void k_cw_rowmax(const float* __restrict__ S, float* __restrict__ Mv){
  const int ofs[4]={0,119,238,341};
  const int wid[4]={119,119,103,103};
  int s = blockIdx.y; int row = blockIdx.x*256+threadIdx.x;
  if (row < 16384){
    const float* p = S + (long)row*444 + ofs[s];
    float m = -3.4e38f;
    int w = wid[s];
    for (int n=0;n<w;n++) m = fmaxf(m, p[n]);
    Mv[(long)s*16384+row] = m;
  }
}
__global__ void k_cw_softmax(const float* __restrict__ Mv, float* __restrict__ att){
  int b=blockIdx.x, s=blockIdx.y, tid=threadIdx.x;
  const float* src = Mv + (long)s*16384 + (long)b*512;
  __shared__ float red[256];
  float v0 = src[tid], v1 = src[tid+256];
  red[tid] = fmaxf(v0,v1); __syncthreads();
  for (int o=128;o>0;o>>=1){ if (tid<o) red[tid]=fmaxf(red[tid],red[tid+o]); __syncthreads(); }
  float m = red[0]; __syncthreads();
  float e0=expf(v0-m), e1=expf(v1-m);
  red[tid]=e0+e1; __syncthreads();
  for (int o=128;o>0;o>>=1){ if (tid<o) red[tid]+=red[tid+o]; __syncthreads(); }
  float inv = 1.f/red[0];
  float* dst = att + ((long)s*32 + b)*512;
  dst[tid]=e0*inv; dst[tid+256]=e1*inv;
}
__global__ void k_cw_out(const float* __restrict__ att, const float* __restrict__ DH, float* __restrict__ outp){
  int b=blockIdx.x, s=blockIdx.y, tid=threadIdx.x;
  __shared__ float a[512];
  for (int i=tid;i<512;i+=256) a[i]=att[((long)s*32+b)*512+i];
  __syncthreads();
  for (int d=tid; d<300; d+=256){
    float acc=0.f;
    for (int t=0;t<512;t++) acc += a[t]*DH[((long)b*512+t)*300+d];
    outp[((long)s*32+b)*300+d]=acc;
  }
}

// ---------------- masked softmax over l=50 (in place) ----------------
__global__ void k_masksm(float* __restrict__ att, long nrows){
  long row = (long)blockIdx.x*256 + threadIdx.x;
  if (row >= nrows) return;
  float* p = att + row*50;
  float m = -INFINITY;
  for (int l=0;l<50;l++){ float a = p[l]; if (a != 0.f && a > m) m = a; }
  if (m == -INFINITY){ for (int l=0;l<50;l++) p[l] = 0.f; return; }
  float s = 0.f;
  for (int l=0;l<50;l++){ float a = p[l]; float e = (a==0.f) ? 0.f : expf(a-m); p[l]=e; s+=e; }
  float inv = 1.f/s;
  for (int l=0;l<50;l++) p[l] *= inv;
}

// ---------------- fact separation combine (rows of 300), 1 wave per row ----------------
// NOTE: no __restrict__ — call 2 intentionally aliases simOut=scen, diffOut=circ.
__global__ void k_factsep(const float* circ, const float* scen,
                          float* simOut, float* diffOut, long nrows)
{
  int lane = threadIdx.x & 63;
  long row = (long)blockIdx.x*4 + (threadIdx.x >> 6);
  if (row >= nrows) return;
  const float* c = circ + row*300;
  const float* s = scen + row*300;
  float x3=0.f, x4=0.f;
  for (int d=lane; d<300; d+=64){ float sv=s[d]; x3 += c[d]*sv; x4 += sv*sv; }
  for (int o=32;o>0;o>>=1){ x3 += __shfl_down(x3,o); x4 += __shfl_down(x4,o); }
  x3 = __shfl(x3,0); x4 = __shfl(x4,0);
  float coef = x3 / (x4 + 1e-10f);
  for (int d=lane; d<300; d+=64){
    float sv = s[d]; float cv = c[d];
    float sim = coef*sv;
    simOut[row*300+d] = sim;
    diffOut[row*300+d] = cv - sim;
  }
}

// ---------------- assemblers ----------------
__global__ void k_factart(const float* __restrict__ DH, const float* __restrict__ dha,
                          const float* __restrict__ adc, const float* __restrict__ db,
                          float* __restrict__ out)
{
  long row = blockIdx.x; int b = (int)(row >> 9);
  for (int c=threadIdx.x; c<1200; c+=256){
    float v;
    if (c < 300) v = DH[row*300 + c];
    else if (c < 600) v = dha[(long)b*300 + (c-300)];
    else if (c < 900) v = adc[row*300 + (c-600)];
    else v = db[(long)b*300 + (c-900)];
    out[row*1200 + c] = v;
  }
}
__global__ void k_termcat(const float* __restrict__ DH, const float* __restrict__ ssc,
                          const float* __restrict__ dsc, float* __restrict__ out){
  long row = blockIdx.x;
  for (int c=threadIdx.x; c<900; c+=256){
    float v = (c<300) ? DH[row*300+c] : (c<600 ? ssc[row*300+(c-300)] : dsc[row*300+(c-600)]);
    out[row*900+c] = v;
  }
}

// ---------------- classifier: logits -> fp32 out, optional argmax ----------------
// feat[b] = concat(s0[b],s1[b],s2[b]) each row len L (null -> fewer segs), times scale
__global__ __launch_bounds__(256) void k_classify(
    const float* __restrict__ s0, const float* __restrict__ s1, const float* __restrict__ s2,
    int L, int Kf, float scale,
    const float* __restrict__ W, const float* __restrict__ bias, int N,
    float* __restrict__ out, int* __restrict__ amax)
{
  int b = blockIdx.x; int tid = threadIdx.x;
  __shared__ float feat[1200];
  __shared__ float logit[128];
  for (int i=tid; i<Kf; i+=256){
    int seg = i / L, c = i % L;
    const float* s = (seg==0) ? s0 : (seg==1 ? s1 : s2);
    feat[i] = s[(long)b*L + c] * scale;
  }
  __syncthreads();
  for (int n=tid; n<N; n+=256){
    float acc = bias[n];
    const float* w = W + (long)n*Kf;
    for (int k=0;k<Kf;k++) acc += feat[k]*w[k];
    out[(long)b*N + n] = acc;
    logit[n] = acc;
  }
  __syncthreads();
  if (amax && tid==0){
    float best = logit[0]; int bi=0;
    for (int n=1;n<N;n++) if (logit[n] > best){ best=logit[n]; bi=n; }
    amax[b] = bi;
  }
}

static inline int cdiv(long a, long b){ return (int)((a + b - 1)/b); }

extern "C" void kernel_launch(void* const* d_in, const int* in_sizes, int n_in,
                              void* d_out, int out_size, void* d_ws, size_t ws_size,
                              hipStream_t stream)
{
  (void)in_sizes; (void)n_in; (void)out_size;
  const float* emb     = (const float*)d_in[0];
  const float* encWih  = (const float*)d_in[1];
  const float* encWhh  = (const float*)d_in[2];
  const float* encbih  = (const float*)d_in[3];
  const float* encbhh  = (const float*)d_in[4];
  const float* cchWih  = (const float*)d_in[5];
  const float* cchWhh  = (const float*)d_in[6];
  const float* cchbih  = (const float*)d_in[7];
  const float* cchbhh  = (const float*)d_in[8];
  const float* termWih = (const float*)d_in[9];
  const float* termWhh = (const float*)d_in[10];
  const float* termbih = (const float*)d_in[11];
  const float* termbhh = (const float*)d_in[12];
  const float* artWih  = (const float*)d_in[13];
  const float* artWhh  = (const float*)d_in[14];
  const float* artbih  = (const float*)d_in[15];
  const float* artbhh  = (const float*)d_in[16];
  const float* Wc      = (const float*)d_in[17];
  const float* bc      = (const float*)d_in[18];
  const float* Wa      = (const float*)d_in[19];
  const float* ba      = (const float*)d_in[20];
  const float* Wt_     = (const float*)d_in[21];
  const float* bt_     = (const float*)d_in[22];
  const int* docs    = (const int*)d_in[23];
  const int* chtok   = (const int*)d_in[24];
  const int* artok   = (const int*)d_in[25];
  const int* chnb    = (const int*)d_in[26];
  const int* chnbm   = (const int*)d_in[27];
  const int* arnb    = (const int*)d_in[28];
  const int* arnbm   = (const int*)d_in[29];
  const int* vchtok  = (const int*)d_in[30];
  const int* vartok  = (const int*)d_in[31];
  float* ob = (float*)d_out;
  float* ws = (float*)d_ws;

  // -------- workspace layout (float elements) --------
  constexpr long O_WTENC = 0;                       // 2*150*450
  constexpr long O_WTCCH = O_WTENC + 135000;        // 2*150*450
  constexpr long O_WTART = O_WTCCH + 135000;        // 2*600*1800
  constexpr long O_WTTERM= O_WTART + 2160000;       // 2*450*1350
  constexpr long O_DH    = O_WTTERM + 1215000;      // 16384*300
  constexpr long O_DMEAN = O_DH + 4915200;          // 32*300
  constexpr long O_CHM   = O_DMEAN + 9600;          // 119*300
  constexpr long O_ARM   = O_CHM + 35700;           // 103*300
  constexpr long O_LAB   = O_ARM + 30900;           // 444*300
  constexpr long O_GDT   = O_LAB + 133200;          // 119*300
  constexpr long O_CWM   = O_GDT + 35700;           // 4*16384
  constexpr long O_CWA   = O_CWM + 65536;           // 4*32*512
  constexpr long O_CWO   = O_CWA + 65536;           // 4*32*300
  constexpr long O_CP    = O_CWO + 38400;           // 64 ints
  constexpr long O_VCH   = O_CP + 64;               // 32*50*300
  constexpr long O_VCHT  = O_VCH + 480000;          // 32*300*50
  constexpr long O_ATT   = O_VCHT + 480000;         // 32*512*50
  constexpr long O_SCEN  = O_ATT + 819200;          // 16384*300
  constexpr long O_ADC   = O_SCEN + 4915200;        // 16384*300
  constexpr long O_SEC   = O_ADC + 4915200;         // 16384*300
  constexpr long O_HBUF  = O_SEC + 4915200;         // 2*2*32*600
  constexpr long O_YSUM  = O_HBUF + 76800;          // 32*1200
  constexpr long O_GATH  = O_YSUM + 38400;          // 16384*200
  constexpr long O_XSS   = O_GATH + 3276800;        // 2*6592*450
  constexpr long O_PF    = O_XSS + 5932800;         // 16384*1200 (xs_doc / S / fact_art / term)
  constexpr long O_XB    = O_PF + 19660800;         // 2*16384*1800 (xs_art / xs_term)
  constexpr long TOTAL   = O_XB + 58982400;         // ~454 MB
  if (ws_size < (size_t)TOTAL * 4) return;          // loud failure if ws too small

  float* WT_ENC = ws + O_WTENC;
  float* WT_CCH = ws + O_WTCCH;
  float* WT_ART = ws + O_WTART;
  float* WT_TERM= ws + O_WTTERM;
  float* DH     = ws + O_DH;
  float* DMEAN  = ws + O_DMEAN;
  float* CHM    = ws + O_CHM;
  float* ARM    = ws + O_ARM;
  float* LAB    = ws + O_LAB;
  float* GDT    = ws + O_GDT;
  float* CWM    = ws + O_CWM;
  float* CWA    = ws + O_CWA;
  float* CWO    = ws + O_CWO;
  int*   CP     = (int*)(ws + O_CP);
  int*   AP     = CP + 32;
  float* VCH    = ws + O_VCH;
  float* VCHT   = ws + O_VCHT;
  float* ATT    = ws + O_ATT;
  float* SCEN   = ws + O_SCEN;
  float* ADC    = ws + O_ADC;
  float* SEC    = ws + O_SEC;
  float* HBUF   = ws + O_HBUF;
  float* YSUM   = ws + O_YSUM;
  float* GATH   = ws + O_GATH;
  float* XSS    = ws + O_XSS;
  float* PF     = ws + O_PF;
  float* XB     = ws + O_XB;

  // -------- transpose all Whh --------
  k_transpose<<<dim3(cdiv(450L*150,256),2),256,0,stream>>>(encWhh, WT_ENC, 450,150);
  k_transpose<<<dim3(cdiv(450L*150,256),2),256,0,stream>>>(cchWhh, WT_CCH, 450,150);
  k_transpose<<<dim3(cdiv(1800L*600,256),2),256,0,stream>>>(artWhh, WT_ART, 1800,600);
  k_transpose<<<dim3(cdiv(1350L*450,256),2),256,0,stream>>>(termWhh, WT_TERM, 1350,450);

  // -------- charge token encoder (encch), mean only --------
  k_gather<<<3808,256,0,stream>>>(emb, chtok, GATH);
  k_gemm_nt<<<dim3(8,cdiv(3808,64),2),256,0,stream>>>(GATH, cchWih, cchbih, XSS,
      3808,450,200, 0, 450L*200, 3808L*450, 450);
  k_gru_small<<<dim3(119,2),512,0,stream>>>(XSS, 3808L*450, WT_CCH, cchbhh,
      nullptr,0, CHM,300, 32);

  // -------- article token encoder (encch), mean only --------
  k_gather<<<6592,256,0,stream>>>(emb, artok, GATH);
  k_gemm_nt<<<dim3(8,cdiv(6592,64),2),256,0,stream>>>(GATH, cchWih, cchbih, XSS,
      6592,450,200, 0, 450L*200, 6592L*450, 450);
  k_gru_small<<<dim3(103,2),512,0,stream>>>(XSS, 6592L*450, WT_CCH, cchbhh,
      nullptr,0, ARM,300, 64);

  // -------- originals + graph decomposition into label-cat --------
  k_copy<<<cdiv(35700,256),256,0,stream>>>(CHM, LAB + 119L*300, 35700);
  k_copy<<<cdiv(30900,256),256,0,stream>>>(ARM, LAB + 341L*300, 30900);
  k_graphdecomp<<<119,256,0,stream>>>(CHM, GDT, chnb, chnbm, 119);
  k_graphdecomp<<<119,256,0,stream>>>(GDT, LAB, chnb, chnbm, 119);
  k_graphdecomp<<<103,256,0,stream>>>(ARM, GDT, arnb, arnbm, 103);
  k_graphdecomp<<<103,256,0,stream>>>(GDT, LAB + 238L*300, arnb, arnbm, 103);

  // -------- document encoder (enc) -> d_hidden + doc_mean --------
  k_gather<<<16384,256,0,stream>>>(emb, docs, GATH);
  k_gemm_nt<<<dim3(8,256,2),256,0,stream>>>(GATH, encWih, encbih, PF,
      16384,450,200, 0, 450L*200, 16384L*450, 450);
  k_gru_small<<<dim3(32,2),512,0,stream>>>(PF, 16384L*450, WT_ENC, encbhh,
      DH,300, DMEAN,300, 512);

  // -------- code_wise (4 label sets at once) --------
  k_gemm_nt<<<dim3(7,256,1),256,0,stream>>>(DH, LAB, nullptr, PF,
      16384,444,300, 0,0,0, 0);
  k_cw_rowmax<<<dim3(64,4),256,0,stream>>>(PF, CWM);
  k_cw_softmax<<<dim3(32,4),256,0,stream>>>(CWM, CWA);
  k_cw_out<<<dim3(32,4),256,0,stream>>>(CWA, DH, CWO);

  // -------- charge classifier + argmax --------
  k_classify<<<32,256,0,stream>>>(DMEAN, CWO, CWO + 32L*300,
      300, 900, 1.f, Wc, bc, 119, ob, CP);

  // -------- verdict-charge GRU (enc) --------
  k_gather_sel<<<dim3(50,32),256,0,stream>>>(emb, vchtok, CP, GATH);
  k_gemm_nt<<<dim3(8,25,2),256,0,stream>>>(GATH, encWih, encbih, XSS,
      1600,450,200, 0, 450L*200, 1600L*450, 450);
  k_gru_small<<<dim3(32,2),512,0,stream>>>(XSS, 1600L*450, WT_ENC, encbhh,
      VCH,300, nullptr,0, 50);

  // -------- fact separation 1 (vch vs d_hidden) --------
  k_gemm_nt<<<dim3(1,8,32),256,0,stream>>>(DH, VCH, nullptr, ATT,
      512,50,300, 512L*300, 50L*300, 512L*50, 0);
  k_masksm<<<64,256,0,stream>>>(ATT, 16384);
  k_transpose<<<dim3(cdiv(15000,256),32),256,0,stream>>>(VCH, VCHT, 50, 300);
  k_gemm_nt<<<dim3(5,8,32),256,0,stream>>>(ATT, VCHT, nullptr, SCEN,
      512,300,50, 512L*50, 300L*50, 512L*300, 0);
  k_factsep<<<4096,256,0,stream>>>(DH, SCEN, ADC, SEC, 16384);

  // -------- fact_article + art bigru --------
  k_factart<<<16384,256,0,stream>>>(DH, CWO + 2L*32*300, ADC, CWO + 3L*32*300, PF);
  k_gemm_nt<<<dim3(cdiv(1800,64),256,2),256,0,stream>>>(PF, artWih, artbih, XB,
      16384,1800,1200, 0, 1800L*1200, 16384L*1800, 1800);
  hipMemsetAsync(HBUF, 0, (76800 + 38400)*sizeof(float), stream);
  for (int t=0; t<512; t++){
    int par = t & 1;
    k_gru_bigstep<<<dim3(60,4,2),256,0,stream>>>(XB, 16384L*1800, WT_ART, artbhh,
        HBUF + (long)par*38400, HBUF + (long)(par^1)*38400, YSUM, 1200, t, 512, 600);
  }
  k_classify<<<32,256,0,stream>>>(YSUM, nullptr, nullptr,
      1200, 1200, 1.f/512.f, Wa, ba, 103, ob + 3808, AP);

  // -------- verdict-article GRU (enc) --------
  k_gather_sel<<<dim3(50,32),256,0,stream>>>(emb, vartok, AP, GATH);
  k_gemm_nt<<<dim3(8,25,2),256,0,stream>>>(GATH, encWih, encbih, XSS,
      1600,450,200, 0, 450L*200, 1600L*450, 450);
  k_gru_small<<<dim3(32,2),512,0,stream>>>(XSS, 1600L*450, WT_ENC, encbhh,
      VCH,300, nullptr,0, 50);

  // -------- fact separation 2 (var vs sec); ssc->SCEN, dsc->SEC in place --------
  k_gemm_nt<<<dim3(1,8,32),256,0,stream>>>(SEC, VCH, nullptr, ATT,
      512,50,300, 512L*300, 50L*300, 512L*50, 0);
  k_masksm<<<64,256,0,stream>>>(ATT, 16384);
  k_transpose<<<dim3(cdiv(15000,256),32),256,0,stream>>>(VCH, VCHT, 50, 300);
  k_gemm_nt<<<dim3(5,8,32),256,0,stream>>>(ATT, VCHT, nullptr, SCEN,
      512,300,50, 512L*50, 300L*50, 512L*300, 0);
  k_factsep<<<4096,256,0,stream>>>(SEC, SCEN, SCEN, SEC, 16384);

  // -------- term bigru --------
  k_termcat<<<16384,256,0,stream>>>(DH, SCEN, SEC, PF);
  k_gemm_nt<<<dim3(cdiv(1350,64),256,2),256,0,stream>>>(PF, termWih, termbih, XB,
      16384,1350,900, 0, 1350L*900, 16384L*1350, 1350);
  hipMemsetAsync(HBUF, 0, (76800 + 38400)*sizeof(float), stream);
  for (int t=0; t<512; t++){
    int par = t & 1;
    k_gru_bigstep<<<dim3(45,4,2),256,0,stream>>>(XB, 16384L*1350, WT_TERM, termbhh,
        HBUF + (long)par*38400, HBUF + (long)(par^1)*38400, YSUM, 900, t, 512, 450);
  }
  k_classify<<<32,256,0,stream>>>(YSUM, nullptr, nullptr,
      900, 900, 1.f/512.f, Wt_, bt_, 11, ob + 7104, nullptr);
}

// Round 3
// 35293.027 us; speedup vs baseline: 1.6880x; 1.6880x over previous
//
#include <hip/hip_runtime.h>
#include <hip/hip_bf16.h>

#define DEVI __device__ __forceinline__

DEVI float sigm(float x){ return 1.f/(1.f+expf(-x)); }

// ---------------- transpose: out[b][c][r] = in[b][r][c] ----------------
__global__ void k_transpose(const float* __restrict__ in, float* __restrict__ out, int R, int C){
  int b = blockIdx.y;
  long n = (long)R*C;
  long i = (long)blockIdx.x*256 + threadIdx.x;
  if (i < n){
    int r = (int)(i / C), c = (int)(i % C);
    out[(long)b*n + (long)c*R + r] = in[(long)b*n + i];
  }
}

// ---------------- embedding gathers (D=200) ----------------
__global__ void k_gather(const float* __restrict__ emb, const int* __restrict__ tok, float* __restrict__ out){
  int row = blockIdx.x; int c = threadIdx.x;
  if (c < 200) out[(long)row*200 + c] = emb[(long)tok[row]*200 + c];
}
__global__ void k_gather_sel(const float* __restrict__ emb, const int* __restrict__ tok, const int* __restrict__ sel, float* __restrict__ out){
  int t = blockIdx.x, b = blockIdx.y; int c = threadIdx.x;
  if (c < 200){
    int tk = tok[(long)sel[b]*50 + t];
    out[((long)b*50 + t)*200 + c] = emb[(long)tk*200 + c];
  }
}

// ---------------- fp32 GEMM 128x128 tile, 8x8 micro: C = A(M,K) @ W(N,K)^T + bias ----------------
__global__ __launch_bounds__(256) void k_gemm128(
    const float* __restrict__ A, const float* __restrict__ W,
    const float* __restrict__ bias, float* __restrict__ C,
    int M, int N, int K, long sA, long sW, long sC, long sBias)
{
  int bz = blockIdx.z;
  A += (long)bz*sA; W += (long)bz*sW; C += (long)bz*sC;
  if (bias) bias += (long)bz*sBias;
  int n0 = blockIdx.x*128, m0 = blockIdx.y*128;
  __shared__ float As[16][132];
  __shared__ float Bs[16][132];
  int tid = threadIdx.x;
  int tx = tid & 15, ty = tid >> 4;
  float acc[8][8] = {};
  const bool k4 = ((K & 3) == 0);
  for (int k0 = 0; k0 < K; k0 += 16){
    #pragma unroll
    for (int half = 0; half < 2; half++){
      int s = tid + half*256;       // 0..511
      int r = s >> 2;               // 0..127
      int kq = (s & 3) << 2;        // 0,4,8,12
      int k = k0 + kq;
      int m = m0 + r;
      float4 va = make_float4(0.f,0.f,0.f,0.f);
      if (m < M){
        if (k4 && k + 3 < K) va = *(const float4*)&A[(long)m*K + k];
        else {
          float* pv = (float*)&va;
          #pragma unroll
          for (int u=0; u<4; u++) if (k+u < K) pv[u] = A[(long)m*K + k + u];
        }
      }
      As[kq+0][r]=va.x; As[kq+1][r]=va.y; As[kq+2][r]=va.z; As[kq+3][r]=va.w;
      int n = n0 + r;
      float4 vb = make_float4(0.f,0.f,0.f,0.f);
      if (n < N){
        if (k4 && k + 3 < K) vb = *(const float4*)&W[(long)n*K + k];
        else {
          float* pv = (float*)&vb;
          #pragma unroll
          for (int u=0; u<4; u++) if (k+u < K) pv[u] = W[(long)n*K + k + u];
        }
      }
      Bs[kq+0][r]=vb.x; Bs[kq+1][r]=vb.y; Bs[kq+2][r]=vb.z; Bs[kq+3][r]=vb.w;
    }
    __syncthreads();
    #pragma unroll
    for (int kk=0;kk<16;kk++){
      float a[8], b[8];
      *(float4*)&a[0] = *(const float4*)&As[kk][ty*8];
      *(float4*)&a[4] = *(const float4*)&As[kk][ty*8+4];
      *(float4*)&b[0] = *(const float4*)&Bs[kk][tx*8];
      *(float4*)&b[4] = *(const float4*)&Bs[kk][tx*8+4];
      #pragma unroll
      for (int i=0;i<8;i++)
        #pragma unroll
        for (int j=0;j<8;j++)
          acc[i][j] += a[i]*b[j];
    }
    __syncthreads();
  }
  #pragma unroll
  for (int i=0;i<8;i++){
    int m = m0 + ty*8 + i;
    if (m >= M) continue;
    #pragma unroll
    for (int j=0;j<8;j++){
      int n = n0 + tx*8 + j;
      if (n < N) C[(long)m*N + n] = acc[i][j] + (bias ? bias[n] : 0.f);
    }
  }
}

// ---------------- small GRU (h=150, 3h=450), 1 wg per (item,dir) ----------------
__global__ __launch_bounds__(512) void k_gru_small(
    const float* __restrict__ xs, long xsDir,
    const float* __restrict__ Wt, const float* __restrict__ bhh,
    float* __restrict__ y, int yld,
    float* __restrict__ meanOut, int meanld,
    int T)
{
  int item = blockIdx.x, dir = blockIdx.y;
  const float* xsd = xs + (long)dir*xsDir + (long)item*T*450;
  const float* Wtd = Wt + (long)dir*150*450;
  int tid = threadIdx.x;
  float bh = (tid < 450) ? bhh[(long)dir*450 + tid] : 0.f;
  __shared__ float hs[152];
  __shared__ float gs[456];
  if (tid < 150) hs[tid] = 0.f;
  float hsum = 0.f;
  __syncthreads();
  for (int t=0;t<T;t++){
    int tt = dir ? (T-1-t) : t;
    if (tid < 450){
      float g = bh;
      const float* wp = Wtd + tid;
      #pragma unroll 5
      for (int k=0;k<150;k++) g += hs[k] * wp[(long)k*450];
      gs[tid] = g;
    }
    __syncthreads();
    if (tid < 150){
      const float* xr = xsd + (long)tt*450;
      float r = sigm(xr[tid]     + gs[tid]);
      float z = sigm(xr[150+tid] + gs[150+tid]);
      float nn = tanhf(xr[300+tid] + r*gs[300+tid]);
      float h = (1.f-z)*nn + z*hs[tid];
      hs[tid] = h;
      hsum += h;
      if (y) y[((long)item*T + tt)*yld + dir*150 + tid] = h;
    }
    __syncthreads();
  }
  if (meanOut && tid < 150)
    meanOut[(long)item*meanld + dir*150 + tid] = hsum / (float)T;
}

// ---------------- big GRU, one launch per timestep ----------------
// Whh in ORIGINAL layout [dir][3h][h] row-major; float2 streaming loads.
__global__ __launch_bounds__(256) void k_gru_bigstep(
    const float* __restrict__ xs, long xsDir,
    const float* __restrict__ Whh, const float* __restrict__ bhh,
    const float* __restrict__ hprev, float* __restrict__ hnext,
    float* __restrict__ ysum, int ysld,
    int t, int T, int h)
{
  const int HC=10, GB=8, B=32;
  int dir = blockIdx.z;
  int c0 = blockIdx.x*HC;
  int b0 = blockIdx.y*GB;
  int h3 = 3*h;
  const float* xsd = xs + (long)dir*xsDir;
  const float* Wd  = Whh + (long)dir*h*h3;
  const float* bhd = bhh + (long)dir*h3;
  const float* hp  = hprev + (long)dir*B*h;
  float* hn = hnext + (long)dir*B*h;
  int tt = dir ? (T-1-t) : t;
  __shared__ float hsl[8*600];
  __shared__ float gl[240];
  int tid = threadIdx.x;
  for (int i=tid; i<GB*h; i+=256)
    hsl[i] = hp[(long)(b0 + i/h)*h + (i%h)];
  __syncthreads();
  if (tid < 3*GB*HC){
    int i = tid % HC;
    int bb = (tid / HC) % GB;
    int g = tid / (HC*GB);
    int gcol = g*h + c0 + i;
    float acc = bhd[gcol];
    const float* hr = &hsl[bb*h];
    const float* wr = Wd + (long)gcol*h;
    #pragma unroll 4
    for (int k=0; k<h; k+=2){
      float2 w  = *(const float2*)&wr[k];
      float2 hv = *(const float2*)&hr[k];
      acc += hv.x*w.x + hv.y*w.y;
    }
    gl[tid] = acc;
  }
  __syncthreads();
  if (tid < GB*HC){
    int i = tid % HC; int bb = tid / HC;
    int c = c0 + i; int b = b0 + bb;
    const float* xr = xsd + ((long)b*T + tt)*h3;
    float r = sigm(xr[c]     + gl[(0*GB+bb)*HC + i]);
    float z = sigm(xr[h+c]   + gl[(1*GB+bb)*HC + i]);
    float nn = tanhf(xr[2*h+c] + r*gl[(2*GB+bb)*HC + i]);
    float hv = hsl[bb*h + c];
    float hne = (1.f-z)*nn + z*hv;
    hn[(long)b*h + c] = hne;
    ysum[(long)b*ysld + dir*h + c] += hne;
  }
}

// ---------------- graph decomposition layer (D=300, K=8) ----------------
__global__ __launch_bounds__(256) void k_graphdecomp(
   const float* __restrict__ labIn, float* __restrict__ labOut,
   const int* __restrict__ nb, const int* __restrict__ nbm, int N)
{
  int n = blockIdx.x; if (n >= N) return;
  int tid = threadIdx.x;
  __shared__ float ln[300];
  __shared__ float red[12];
  for (int d=tid; d<300; d+=256) ln[d] = labIn[(long)n*300+d];
  float deg = 0.f;
  for (int k=0;k<8;k++) deg += (float)nbm[n*8+k];
  float invdeg = 1.f / fmaxf(deg, 1.f);
  float acc0 = 0.f, acc1 = 0.f;
  __syncthreads();
  for (int k=0;k<8;k++){
    int j = nb[n*8+k];
    float mk = (float)nbm[n*8+k];
    const float* lj = labIn + (long)j*300;
    float p1=0.f, p2=0.f;
    for (int d=tid; d<300; d+=256){ float v = lj[d]; p1 += ln[d]*v; p2 += v*v; }
    for (int o=32;o>0;o>>=1){ p1 += __shfl_down(p1,o); p2 += __shfl_down(p2,o); }
    __syncthreads();
    int w = tid>>6, lane = tid&63;
    if (lane==0){ red[w]=p1; red[4+w]=p2; }
    __syncthreads();
    float x1 = red[0]+red[1]+red[2]+red[3];
    float x2 = red[4]+red[5]+red[6]+red[7];
    float coef = (x1 / (x2 + 1e-10f)) * mk * invdeg;
    acc0 += coef * lj[tid];
    if (tid + 256 < 300) acc1 += coef * lj[tid+256];
    __syncthreads();
  }
  bool pos = deg > 0.f;
  labOut[(long)n*300 + tid]                       = pos ? (ln[tid]     - acc0) : ln[tid];
  if (tid+256 < 300) labOut[(long)n*300 + tid+256] = pos ? (ln[tid+256] - acc1) : ln[tid+256];
}

// ---------------- copy ----------------
__global__ void k_copy(const float* __restrict__ src, float* __restrict__ dst, long n){
  long i = (long)blockIdx.x*256+threadIdx.x; if (i<n) dst[i]=src[i];
}

// ---------------- code_wise reductions ----------------
__global__ void k_cw_rowmax(const float* __restrict__ S, float* __restrict__ Mv){
  const int ofs[4]={0,119,238,341};
  const int wid[4]={119,119,103,103};
  int s = blockIdx.y; int row = blockIdx.x*256+threadIdx.x;
  if (row < 16384){
    const float* p = S + (long)row*444 + ofs[s];
    float m = -3.4e38f;
    int w = wid[s];
    for (int n=0;n<w;n++) m = fmaxf(m, p[n]);
    Mv[(long)s*16384+row] = m;
  }
}
__global__ void k_cw_softmax(const float* __restrict__ Mv, float* __restrict__ att){
  int b=blockIdx.x, s=blockIdx.y, tid=threadIdx.x;
  const float* src = Mv + (long)s*16384 + (long)b*512;
  __shared__ float red[256];
  float v0 = src[tid], v1 = src[tid+256];
  red[tid] = fmaxf(v0,v1); __syncthreads();
  for (int o=128;o>0;o>>=1){ if (tid<o) red[tid]=fmaxf(red[tid],red[tid+o]); __syncthreads(); }
  float m = red[0]; __syncthreads();
  float e0=expf(v0-m), e1=expf(v1-m);
  red[tid]=e0+e1; __syncthreads();
  for (int o=128;o>0;o>>=1){ if (tid<o) red[tid]+=red[tid+o]; __syncthreads(); }
  float inv = 1.f/red[0];
  float* dst = att + ((long)s*32 + b)*512;
  dst[tid]=e0*inv; dst[tid+256]=e1*inv;
}
__global__ void k_cw_out(const float* __restrict__ att, const float* __restrict__ DH, float* __restrict__ outp){
  int b=blockIdx.x, s=blockIdx.y, tid=threadIdx.x;
  __shared__ float a[512];
  for (int i=tid;i<512;i+=256) a[i]=att[((long)s*32+b)*512+i];
  __syncthreads();
  for (int d=tid; d<300; d+=256){
    float acc=0.f;
    for (int t=0;t<512;t++) acc += a[t]*DH[((long)b*512+t)*300+d];
    outp[((long)s*32+b)*300+d]=acc;
  }
}

// ---------------- masked softmax over l=50 (in place) ----------------
__global__ void k_masksm(float* __restrict__ att, long nrows){
  long row = (long)blockIdx.x*256 + threadIdx.x;
  if (row >= nrows) return;
  float* p = att + row*50;
  float m = -INFINITY;
  for (int l=0;l<50;l++){ float a = p[l]; if (a != 0.f && a > m) m = a; }
  if (m == -INFINITY){ for (int l=0;l<50;l++) p[l] = 0.f; return; }
  float s = 0.f;
  for (int l=0;l<50;l++){ float a = p[l]; float e = (a==0.f) ? 0.f : expf(a-m); p[l]=e; s+=e; }
  float inv = 1.f/s;
  for (int l=0;l<50;l++) p[l] *= inv;
}

// ---------------- fact separation combine (rows of 300), 1 wave per row ----------------
// NOTE: no __restrict__ — call 2 intentionally aliases simOut=scen, diffOut=circ.
__global__ void k_factsep(const float* circ, const float* scen,
                          float* simOut, float* diffOut, long nrows)
{
  int lane = threadIdx.x & 63;
  long row = (long)blockIdx.x*4 + (threadIdx.x >> 6);
  if (row >= nrows) return;
  const float* c = circ + row*300;
  const float* s = scen + row*300;
  float x3=0.f, x4=0.f;
  for (int d=lane; d<300; d+=64){ float sv=s[d]; x3 += c[d]*sv; x4 += sv*sv; }
  for (int o=32;o>0;o>>=1){ x3 += __shfl_down(x3,o); x4 += __shfl_down(x4,o); }
  x3 = __shfl(x3,0); x4 = __shfl(x4,0);
  float coef = x3 / (x4 + 1e-10f);
  for (int d=lane; d<300; d+=64){
    float sv = s[d]; float cv = c[d];
    float sim = coef*sv;
    simOut[row*300+d] = sim;
    diffOut[row*300+d] = cv - sim;
  }
}

// ---------------- assemblers ----------------
__global__ void k_factart(const float* __restrict__ DH, const float* __restrict__ dha,
                          const float* __restrict__ adc, const float* __restrict__ db,
                          float* __restrict__ out)
{
  long row = blockIdx.x; int b = (int)(row >> 9);
  for (int c=threadIdx.x; c<1200; c+=256){
    float v;
    if (c < 300) v = DH[row*300 + c];
    else if (c < 600) v = dha[(long)b*300 + (c-300)];
    else if (c < 900) v = adc[row*300 + (c-600)];
    else v = db[(long)b*300 + (c-900)];
    out[row*1200 + c] = v;
  }
}
__global__ void k_termcat(const float* __restrict__ DH, const float* __restrict__ ssc,
                          const float* __restrict__ dsc, float* __restrict__ out){
  long row = blockIdx.x;
  for (int c=threadIdx.x; c<900; c+=256){
    float v = (c<300) ? DH[row*300+c] : (c<600 ? ssc[row*300+(c-300)] : dsc[row*300+(c-600)]);
    out[row*900+c] = v;
  }
}

// ---------------- classifier: logits -> fp32 out, optional argmax ----------------
__global__ __launch_bounds__(256) void k_classify(
    const float* __restrict__ s0, const float* __restrict__ s1, const float* __restrict__ s2,
    int L, int Kf, float scale,
    const float* __restrict__ W, const float* __restrict__ bias, int N,
    float* __restrict__ out, int* __restrict__ amax)
{
  int b = blockIdx.x; int tid = threadIdx.x;
  __shared__ float feat[1200];
  __shared__ float logit[128];
  for (int i=tid; i<Kf; i+=256){
    int seg = i / L, c = i % L;
    const float* s = (seg==0) ? s0 : (seg==1 ? s1 : s2);
    feat[i] = s[(long)b*L + c] * scale;
  }
  __syncthreads();
  for (int n=tid; n<N; n+=256){
    float acc = bias[n];
    const float* w = W + (long)n*Kf;
    for (int k=0;k<Kf;k++) acc += feat[k]*w[k];
    out[(long)b*N + n] = acc;
    logit[n] = acc;
  }
  __syncthreads();
  if (amax && tid==0){
    float best = logit[0]; int bi=0;
    for (int n=1;n<N;n++) if (logit[n] > best){ best=logit[n]; bi=n; }
    amax[b] = bi;
  }
}

static inline int cdiv(long a, long b){ return (int)((a + b - 1)/b); }

extern "C" void kernel_launch(void* const* d_in, const int* in_sizes, int n_in,
                              void* d_out, int out_size, void* d_ws, size_t ws_size,
                              hipStream_t stream)
{
  (void)in_sizes; (void)n_in; (void)out_size;
  const float* emb     = (const float*)d_in[0];
  const float* encWih  = (const float*)d_in[1];
  const float* encWhh  = (const float*)d_in[2];
  const float* encbih  = (const float*)d_in[3];
  const float* encbhh  = (const float*)d_in[4];
  const float* cchWih  = (const float*)d_in[5];
  const float* cchWhh  = (const float*)d_in[6];
  const float* cchbih  = (const float*)d_in[7];
  const float* cchbhh  = (const float*)d_in[8];
  const float* termWih = (const float*)d_in[9];
  const float* termWhh = (const float*)d_in[10];
  const float* termbih = (const float*)d_in[11];
  const float* termbhh = (const float*)d_in[12];
  const float* artWih  = (const float*)d_in[13];
  const float* artWhh  = (const float*)d_in[14];
  const float* artbih  = (const float*)d_in[15];
  const float* artbhh  = (const float*)d_in[16];
  const float* Wc      = (const float*)d_in[17];
  const float* bc      = (const float*)d_in[18];
  const float* Wa      = (const float*)d_in[19];
  const float* ba      = (const float*)d_in[20];
  const float* Wt_     = (const float*)d_in[21];
  const float* bt_     = (const float*)d_in[22];
  const int* docs    = (const int*)d_in[23];
  const int* chtok   = (const int*)d_in[24];
  const int* artok   = (const int*)d_in[25];
  const int* chnb    = (const int*)d_in[26];
  const int* chnbm   = (const int*)d_in[27];
  const int* arnb    = (const int*)d_in[28];
  const int* arnbm   = (const int*)d_in[29];
  const int* vchtok  = (const int*)d_in[30];
  const int* vartok  = (const int*)d_in[31];
  float* ob = (float*)d_out;
  float* ws = (float*)d_ws;

  // -------- workspace layout (float elements) --------
  constexpr long O_WTENC = 0;                       // 2*150*450
  constexpr long O_WTCCH = O_WTENC + 135000;        // 2*150*450
  constexpr long O_WTART = O_WTCCH + 135000;        // (unused now)
  constexpr long O_WTTERM= O_WTART + 2160000;       // (unused now)
  constexpr long O_DH    = O_WTTERM + 1215000;      // 16384*300
  constexpr long O_DMEAN = O_DH + 4915200;          // 32*300
  constexpr long O_CHM   = O_DMEAN + 9600;          // 119*300
  constexpr long O_ARM   = O_CHM + 35700;           // 103*300
  constexpr long O_LAB   = O_ARM + 30900;           // 444*300
  constexpr long O_GDT   = O_LAB + 133200;          // 119*300
  constexpr long O_CWM   = O_GDT + 35700;           // 4*16384
  constexpr long O_CWA   = O_CWM + 65536;           // 4*32*512
  constexpr long O_CWO   = O_CWA + 65536;           // 4*32*300
  constexpr long O_CP    = O_CWO + 38400;           // 64 ints
  constexpr long O_VCH   = O_CP + 64;               // 32*50*300
  constexpr long O_VCHT  = O_VCH + 480000;          // 32*300*50
  constexpr long O_ATT   = O_VCHT + 480000;         // 32*512*50
  constexpr long O_SCEN  = O_ATT + 819200;          // 16384*300
  constexpr long O_ADC   = O_SCEN + 4915200;        // 16384*300
  constexpr long O_SEC   = O_ADC + 4915200;         // 16384*300
  constexpr long O_HBUF  = O_SEC + 4915200;         // 2*2*32*600
  constexpr long O_YSUM  = O_HBUF + 76800;          // 32*1200
  constexpr long O_GATH  = O_YSUM + 38400;          // 16384*200
  constexpr long O_XSS   = O_GATH + 3276800;        // 2*6592*450
  constexpr long O_PF    = O_XSS + 5932800;         // 16384*1200
  constexpr long O_XB    = O_PF + 19660800;         // 2*16384*1800
  constexpr long TOTAL   = O_XB + 58982400;         // ~454 MB
  if (ws_size < (size_t)TOTAL * 4) return;

  float* WT_ENC = ws + O_WTENC;
  float* WT_CCH = ws + O_WTCCH;
  float* DH     = ws + O_DH;
  float* DMEAN  = ws + O_DMEAN;
  float* CHM    = ws + O_CHM;
  float* ARM    = ws + O_ARM;
  float* LAB    = ws + O_LAB;
  float* GDT    = ws + O_GDT;
  float* CWM    = ws + O_CWM;
  float* CWA    = ws + O_CWA;
  float* CWO    = ws + O_CWO;
  int*   CP     = (int*)(ws + O_CP);
  int*   AP     = CP + 32;
  float* VCH    = ws + O_VCH;
  float* VCHT   = ws + O_VCHT;
  float* ATT    = ws + O_ATT;
  float* SCEN   = ws + O_SCEN;
  float* ADC    = ws + O_ADC;
  float* SEC    = ws + O_SEC;
  float* HBUF   = ws + O_HBUF;
  float* YSUM   = ws + O_YSUM;
  float* GATH   = ws + O_GATH;
  float* XSS    = ws + O_XSS;
  float* PF     = ws + O_PF;
  float* XB     = ws + O_XB;

  // -------- transpose small Whh (enc/cch only; big GRUs use original layout) --------
  k_transpose<<<dim3(cdiv(450L*150,256),2),256,0,stream>>>(encWhh, WT_ENC, 450,150);
  k_transpose<<<dim3(cdiv(450L*150,256),2),256,0,stream>>>(cchWhh, WT_CCH, 450,150);

  // -------- charge token encoder (encch), mean only --------
  k_gather<<<3808,256,0,stream>>>(emb, chtok, GATH);
  k_gemm128<<<dim3(4,cdiv(3808,128),2),256,0,stream>>>(GATH, cchWih, cchbih, XSS,
      3808,450,200, 0, 450L*200, 3808L*450, 450);
  k_gru_small<<<dim3(119,2),512,0,stream>>>(XSS, 3808L*450, WT_CCH, cchbhh,
      nullptr,0, CHM,300, 32);

  // -------- article token encoder (encch), mean only --------
  k_gather<<<6592,256,0,stream>>>(emb, artok, GATH);
  k_gemm128<<<dim3(4,cdiv(6592,128),2),256,0,stream>>>(GATH, cchWih, cchbih, XSS,
      6592,450,200, 0, 450L*200, 6592L*450, 450);
  k_gru_small<<<dim3(103,2),512,0,stream>>>(XSS, 6592L*450, WT_CCH, cchbhh,
      nullptr,0, ARM,300, 64);

  // -------- originals + graph decomposition into label-cat --------
  k_copy<<<cdiv(35700,256),256,0,stream>>>(CHM, LAB + 119L*300, 35700);
  k_copy<<<cdiv(30900,256),256,0,stream>>>(ARM, LAB + 341L*300, 30900);
  k_graphdecomp<<<119,256,0,stream>>>(CHM, GDT, chnb, chnbm, 119);
  k_graphdecomp<<<119,256,0,stream>>>(GDT, LAB, chnb, chnbm, 119);
  k_graphdecomp<<<103,256,0,stream>>>(ARM, GDT, arnb, arnbm, 103);
  k_graphdecomp<<<103,256,0,stream>>>(GDT, LAB + 238L*300, arnb, arnbm, 103);

  // -------- document encoder (enc) -> d_hidden + doc_mean --------
  k_gather<<<16384,256,0,stream>>>(emb, docs, GATH);
  k_gemm128<<<dim3(4,128,2),256,0,stream>>>(GATH, encWih, encbih, PF,
      16384,450,200, 0, 450L*200, 16384L*450, 450);
  k_gru_small<<<dim3(32,2),512,0,stream>>>(PF, 16384L*450, WT_ENC, encbhh,
      DH,300, DMEAN,300, 512);

  // -------- code_wise (4 label sets at once) --------
  k_gemm128<<<dim3(4,128,1),256,0,stream>>>(DH, LAB, nullptr, PF,
      16384,444,300, 0,0,0, 0);
  k_cw_rowmax<<<dim3(64,4),256,0,stream>>>(PF, CWM);
  k_cw_softmax<<<dim3(32,4),256,0,stream>>>(CWM, CWA);
  k_cw_out<<<dim3(32,4),256,0,stream>>>(CWA, DH, CWO);

  // -------- charge classifier + argmax --------
  k_classify<<<32,256,0,stream>>>(DMEAN, CWO, CWO + 32L*300,
      300, 900, 1.f, Wc, bc, 119, ob, CP);

  // -------- verdict-charge GRU (enc) --------
  k_gather_sel<<<dim3(50,32),256,0,stream>>>(emb, vchtok, CP, GATH);
  k_gemm128<<<dim3(4,13,2),256,0,stream>>>(GATH, encWih, encbih, XSS,
      1600,450,200, 0, 450L*200, 1600L*450, 450);
  k_gru_small<<<dim3(32,2),512,0,stream>>>(XSS, 1600L*450, WT_ENC, encbhh,
      VCH,300, nullptr,0, 50);

  // -------- fact separation 1 (vch vs d_hidden) --------
  k_gemm128<<<dim3(1,4,32),256,0,stream>>>(DH, VCH, nullptr, ATT,
      512,50,300, 512L*300, 50L*300, 512L*50, 0);
  k_masksm<<<64,256,0,stream>>>(ATT, 16384);
  k_transpose<<<dim3(cdiv(15000,256),32),256,0,stream>>>(VCH, VCHT, 50, 300);
  k_gemm128<<<dim3(3,4,32),256,0,stream>>>(ATT, VCHT, nullptr, SCEN,
      512,300,50, 512L*50, 300L*50, 512L*300, 0);
  k_factsep<<<4096,256,0,stream>>>(DH, SCEN, ADC, SEC, 16384);

  // -------- fact_article + art bigru --------
  k_factart<<<16384,256,0,stream>>>(DH, CWO + 2L*32*300, ADC, CWO + 3L*32*300, PF);
  k_gemm128<<<dim3(cdiv(1800,128),128,2),256,0,stream>>>(PF, artWih, artbih, XB,
      16384,1800,1200, 0, 1800L*1200, 16384L*1800, 1800);
  hipMemsetAsync(HBUF, 0, (76800 + 38400)*sizeof(float), stream);
  for (int t=0; t<512; t++){
    int par = t & 1;
    k_gru_bigstep<<<dim3(60,4,2),256,0,stream>>>(XB, 16384L*1800, artWhh, artbhh,
        HBUF + (long)par*38400, HBUF + (long)(par^1)*38400, YSUM, 1200, t, 512, 600);
  }
  k_classify<<<32,256,0,stream>>>(YSUM, nullptr, nullptr,
      1200, 1200, 1.f/512.f, Wa, ba, 103, ob + 3808, AP);

  // -------- verdict-article GRU (enc) --------
  k_gather_sel<<<dim3(50,32),256,0,stream>>>(emb, vartok, AP, GATH);
  k_gemm128<<<dim3(4,13,2),256,0,stream>>>(GATH, encWih, encbih, XSS,
      1600,450,200, 0, 450L*200, 1600L*450, 450);
  k_gru_small<<<dim3(32,2),512,0,stream>>>(XSS, 1600L*450, WT_ENC, encbhh,
      VCH,300, nullptr,0, 50);

  // -------- fact separation 2 (var vs sec); ssc->SCEN, dsc->SEC in place --------
  k_gemm128<<<dim3(1,4,32),256,0,stream>>>(SEC, VCH, nullptr, ATT,
      512,50,300, 512L*300, 50L*300, 512L*50, 0);
  k_masksm<<<64,256,0,stream>>>(ATT, 16384);
  k_transpose<<<dim3(cdiv(15000,256),32),256,0,stream>>>(VCH, VCHT, 50, 300);
  k_gemm128<<<dim3(3,4,32),256,0,stream>>>(ATT, VCHT, nullptr, SCEN,
      512,300,50, 512L*50, 300L*50, 512L*300, 0);
  k_factsep<<<4096,256,0,stream>>>(SEC, SCEN, SCEN, SEC, 16384);

  // -------- term bigru --------
  k_termcat<<<16384,256,0,stream>>>(DH, SCEN, SEC, PF);
  k_gemm128<<<dim3(cdiv(1350,128),128,2),256,0,stream>>>(PF, termWih, termbih, XB,
      16384,1350,900, 0, 1350L*900, 16384L*1350, 1350);
  hipMemsetAsync(HBUF, 0, (76800 + 38400)*sizeof(float), stream);
  for (int t=0; t<512; t++){
    int par = t & 1;
    k_gru_bigstep<<<dim3(45,4,2),256,0,stream>>>(XB, 16384L*1350, termWhh, termbhh,
        HBUF + (long)par*38400, HBUF + (long)(par^1)*38400, YSUM, 900, t, 512, 450);
  }
  k_classify<<<32,256,0,stream>>>(YSUM, nullptr, nullptr,
      900, 900, 1.f/512.f, Wt_, bt_, 11, ob + 7104, nullptr);
}